// Round 6
// baseline (198.440 us; speedup 1.0000x reference)
//
#include <hip/hip_runtime.h>
#include <hip/hip_bf16.h>

#define T_SEQ 2048
#define NBATCH 8
#define EMB 1024
#define HD 128

typedef _Float16 f16_t;
typedef _Float16 f16x8 __attribute__((ext_vector_type(8)));
typedef _Float16 f16x4 __attribute__((ext_vector_type(4)));
typedef float f32x4 __attribute__((ext_vector_type(4)));

// Tiled layouts — every MFMA fragment load is 16B/lane dense:
//  q2/k2 : [tt=row/16][hc=h/8(16)][r16=row%16][8]   idx = tt*2048 + hc*128 + r16*8 + h%8
//  v2    : [sc=row/8][h(128)][8]                    idx = sc*1024 + h*8 + row%8
//  w2    : [ntile=n/16(24)][kc8=k/8(128)][r16=n%16][8]
// No softmax max-subtraction (|S|<~4, exp fp32-safe; validated prior session).
// R4 lesson: per-lane scattered A-fragment global loads (4KB row stride) are
// ~8x the VMEM transactions of 4-lanes-per-row staging -> keep A staged.
// R5: swapped QK^T (mfma(K,Q)) makes S^T's C-frag (t=l15, s=quad*4+r) exactly
// the 16x16x16 PV A-frag layout -> P stays in registers, no Pl, no per-chunk
// barriers in attn_out. NOTE gfx950 builtin name: mfma_f32_16x16x16f16
// (legacy K=16 names have no underscore before the dtype).

// async global->LDS, 16B per lane
__device__ __forceinline__ void g2l(const f16_t* g, f16_t* l) {
    __builtin_amdgcn_global_load_lds(
        (const __attribute__((address_space(1))) unsigned int*)g,
        (__attribute__((address_space(3))) unsigned int*)l, 16, 0, 0);
}

// ---------------------------------------------------------------------------
// Kernel 1: fused prep (unchanged from R0-verified).
// ---------------------------------------------------------------------------
__global__ __launch_bounds__(256) void prep(
    const float* __restrict__ Wk, const float* __restrict__ bk,
    const float* __restrict__ Wq, const float* __restrict__ bq,
    const float* __restrict__ Wv, const float* __restrict__ bv,
    f16_t* __restrict__ w2, float* __restrict__ biasc,
    float4* __restrict__ out4, float4* __restrict__ colsum4) {
    int bid = blockIdx.x;
    int t = threadIdx.x;
    if (bid < 384) {
        int n = bid;
        const float scale = 0.08838834764831845f;  // HEAD^-0.5
        const float* W; const float* bias; float sc; int col;
        if (n < 128)      { W = Wq; bias = bq; sc = scale; col = n; }
        else if (n < 256) { W = Wk; bias = bk; sc = 1.0f;  col = n - 128; }
        else              { W = Wv; bias = bv; sc = 1.0f;  col = n - 256; }
        if (t < 128) {
            int k0 = t * 8;
            f16x8 v;
            #pragma unroll
            for (int i = 0; i < 8; ++i) v[i] = (f16_t)(W[(size_t)(k0 + i) * HD + col] * sc);
            *(f16x8*)&w2[(size_t)(n >> 4) * 16384 + (size_t)(k0 >> 3) * 128 + (n & 15) * 8] = v;
        }
        if (t == 0) biasc[n] = bias[col] * sc;
    } else if (bid < 384 + 2048) {
        out4[(size_t)(bid - 384) * 256 + t] = make_float4(0.f, 0.f, 0.f, 0.f);
    } else {
        colsum4[(size_t)(bid - 2432) * 256 + t] = make_float4(0.f, 0.f, 0.f, 0.f);
    }
}

// ---------------------------------------------------------------------------
// Kernel 2: QKV GEMM — EXACT R3 v3 (43.0us verified best). 768 blocks,
// 64x128 tiles, A staged coalesced (4 lanes/row), B LDS double-buffered via
// g2l, single barrier per chunk.
// ---------------------------------------------------------------------------
__global__ __launch_bounds__(256) void qkv_gemm(
    const float* __restrict__ X, const f16_t* __restrict__ w2,
    const float* __restrict__ biasc,
    f16_t* __restrict__ q2, f16_t* __restrict__ k2, f16_t* __restrict__ v2) {
    __shared__ f16_t Xs[2][64 * 72];
    __shared__ __align__(16) f16_t Bl[2][8 * 1024];

    int bid = blockIdx.x;
    int r8 = bid & 7, g = bid >> 3;
    int band = (g / 3) * 8 + r8;             // 64-row band, XCD-affine
    int i = g % 3;
    int m0 = band * 64, n0 = i * 128;
    int tid = threadIdx.x;
    int lane = tid & 63, w = tid >> 6;
    int quad = lane >> 4, l15 = lane & 15;
    int msub = (w & 1) * 32, nsub = (w >> 1) * 64;

    int srow = tid >> 2;           // 0..63
    int scg  = (tid & 3) * 16;     // 16-float group within BK=64

    const float* xrow = X + (size_t)(m0 + srow) * EMB + scg;
    const f16_t* bbase = w2 + (size_t)(n0 >> 4) * 16384;

    f32x4 acc[2][4] = {};
    float4 pf[4];

    auto loadA = [&](int kc) {
        #pragma unroll
        for (int u = 0; u < 4; ++u) pf[u] = *(const float4*)(xrow + kc * 64 + u * 4);
    };
    auto stageB = [&](int kc, int buf) {
        const f16_t* bsrc = bbase + (size_t)kc * 1024;
        #pragma unroll
        for (int ii = 0; ii < 4; ++ii) {
            int D = tid * 16 + ii * 4096;                 // byte offset in 16KB
            g2l(bsrc + (size_t)(D >> 11) * 16384 + ((D & 2047) >> 1),
                &Bl[buf][D >> 1]);
        }
    };
    auto stageA = [&](int buf) {
        union { f16_t h[8]; uint4 u4; } p0, p1;
        p0.h[0] = (f16_t)pf[0].x; p0.h[1] = (f16_t)pf[0].y;
        p0.h[2] = (f16_t)pf[0].z; p0.h[3] = (f16_t)pf[0].w;
        p0.h[4] = (f16_t)pf[1].x; p0.h[5] = (f16_t)pf[1].y;
        p0.h[6] = (f16_t)pf[1].z; p0.h[7] = (f16_t)pf[1].w;
        p1.h[0] = (f16_t)pf[2].x; p1.h[1] = (f16_t)pf[2].y;
        p1.h[2] = (f16_t)pf[2].z; p1.h[3] = (f16_t)pf[2].w;
        p1.h[4] = (f16_t)pf[3].x; p1.h[5] = (f16_t)pf[3].y;
        p1.h[6] = (f16_t)pf[3].z; p1.h[7] = (f16_t)pf[3].w;
        *(uint4*)&Xs[buf][srow * 72 + scg] = p0.u4;
        *(uint4*)&Xs[buf][srow * 72 + scg + 8] = p1.u4;
    };
    auto compute = [&](int buf) {
        #pragma unroll
        for (int ks = 0; ks < 2; ++ks) {
            f16x8 afr0 = *(const f16x8*)&Xs[buf][(msub + l15) * 72 + ks * 32 + quad * 8];
            f16x8 afr1 = *(const f16x8*)&Xs[buf][(msub + 16 + l15) * 72 + ks * 32 + quad * 8];
            #pragma unroll
            for (int nf = 0; nf < 4; ++nf) {
                int ntl = (nsub >> 4) + nf;
                f16x8 bfr = *(const f16x8*)&Bl[buf][ntl * 1024 + (ks * 4 + quad) * 128 + l15 * 8];
                acc[0][nf] = __builtin_amdgcn_mfma_f32_16x16x32_f16(afr0, bfr, acc[0][nf], 0, 0, 0);
                acc[1][nf] = __builtin_amdgcn_mfma_f32_16x16x32_f16(afr1, bfr, acc[1][nf], 0, 0, 0);
            }
        }
    };

    // prologue: fill buffer 0
    loadA(0);
    stageB(0, 0);
    stageA(0);
    __syncthreads();

    for (int kc = 0; kc < 16; ++kc) {
        int cur = kc & 1, nxt = cur ^ 1;
        if (kc + 1 < 16) {
            loadA(kc + 1);
            stageB(kc + 1, nxt);
        }
        compute(cur);
        if (kc + 1 < 16) stageA(nxt);
        __syncthreads();
    }

    // epilogue -> tiled layouts
    #pragma unroll
    for (int nf = 0; nf < 4; ++nf) {
        int ng = n0 + nsub + nf * 16 + l15;
        float bval = biasc[ng];
        #pragma unroll
        for (int mf = 0; mf < 2; ++mf) {
            int rowg = m0 + msub + mf * 16 + quad * 4;
            f32x4 a = acc[mf][nf];
            if (ng < 256) {
                f16_t* dst = (ng < 128) ? q2 : k2;
                int c = ng & 127;
                #pragma unroll
                for (int r = 0; r < 4; ++r) {
                    int row = rowg + r;
                    dst[(size_t)(row >> 4) * 2048 + (c >> 3) * 128 + (row & 15) * 8 + (c & 7)]
                        = (f16_t)(a[r] + bval);
                }
            } else {
                int h = ng - 256;
                f16x4 hv;
                #pragma unroll
                for (int r = 0; r < 4; ++r) hv[r] = (f16_t)(a[r] + bval);
                *(f16x4*)&v2[(size_t)(rowg >> 3) * 1024 + h * 8 + (rowg & 7)] = hv;
            }
        }
    }
}

// ---------------------------------------------------------------------------
// Kernel 3: column sums — R4 v2 (barrier-free, direct L2 reads). Unchanged.
// ---------------------------------------------------------------------------
__global__ __launch_bounds__(256, 4) void col_stats(
    const f16_t* __restrict__ q2, const f16_t* __restrict__ k2,
    float* __restrict__ colsum) {
    int bid = blockIdx.x;
    int b = bid & 7;
    int item = 143 - (bid >> 3);
    int cg = 0, slab = 0, cum = 0;
    for (int c = 0; c < 32; ++c) {
        int n = (32 - c + 3) >> 2;
        if (item < cum + n) { cg = c; slab = item - cum; break; }
        cum += n;
    }
    int tc0 = cg + slab * 4, tc1 = min(tc0 + 4, 32);

    int tid = threadIdx.x, lane = tid & 63, w = tid >> 6;
    int quad = lane >> 4, l15 = lane & 15;
    int brow = b * 128;
    size_t base = (size_t)b * T_SEQ;

    f16x8 bfrs[4][4];
    #pragma unroll
    for (int st = 0; st < 4; ++st) {
        const f16_t* kt = k2 + (size_t)(brow + cg * 4 + st) * 2048 + l15 * 8;
        #pragma unroll
        for (int kf = 0; kf < 4; ++kf)
            bfrs[st][kf] = *(const f16x8*)(kt + (kf * 4 + quad) * 128);
    }

    float lacc[4] = {0.f, 0.f, 0.f, 0.f};

    for (int tc = tc0; tc < tc1; ++tc) {
        int tb = tc * 64;
        f16x8 afr[4];
        const f16_t* qt = q2 + (size_t)(brow + tc * 4 + w) * 2048 + l15 * 8;
        #pragma unroll
        for (int kf = 0; kf < 4; ++kf)
            afr[kf] = *(const f16x8*)(qt + (kf * 4 + quad) * 128);
        #pragma unroll
        for (int st = 0; st < 4; ++st) {
            f32x4 s = {};
            #pragma unroll
            for (int kf = 0; kf < 4; ++kf)
                s = __builtin_amdgcn_mfma_f32_16x16x32_f16(afr[kf], bfrs[st][kf], s, 0, 0, 0);
            int scol = cg * 64 + st * 16 + l15;
            #pragma unroll
            for (int r = 0; r < 4; ++r) {
                int t = tb + w * 16 + quad * 4 + r;
                if (t >= scol) lacc[st] += __expf(s[r]);
            }
        }
    }

    #pragma unroll
    for (int st = 0; st < 4; ++st) {
        float v = lacc[st];
        v += __shfl_xor(v, 16, 64);
        v += __shfl_xor(v, 32, 64);
        if (quad == 0) atomicAdd(&colsum[base + cg * 64 + st * 16 + l15], v);
    }
}

// ---------------------------------------------------------------------------
// Kernel 4 (v3, SWAPPED): S^T = mfma(K,Q) puts P in the exact 16x16x16 PV
// A-frag layout (t=l15, s=quad*4+r) -> P never leaves registers. No Pl, no
// per-chunk barriers; waves independent over s16-stripes. Once-per-block
// LDS reduce of the 32x128 tile (4 barriers total) then one atomic pass.
// ---------------------------------------------------------------------------
__global__ __launch_bounds__(256, 3) void attn_out(
    const f16_t* __restrict__ q2, const f16_t* __restrict__ k2,
    const f16_t* __restrict__ v2, const float* __restrict__ colsum,
    float* __restrict__ out) {
    __shared__ float Or[32 * 128];   // 16 KiB block-output reduce buffer

    int bid = blockIdx.x;
    int b = bid & 7;
    int item = 159 - (bid >> 3);
    int g = 0, slab = 0, cum = 0;
    for (int gg = 0; gg < 64; ++gg) {
        int n = (((gg >> 1) + 1) + 7) >> 3;
        if (item < cum + n) { g = gg; slab = item - cum; break; }
        cum += n;
    }
    int nch = (g >> 1) + 1;
    int c0 = slab * 8, c1 = min(c0 + 8, nch);
    int trow = g * 32;

    int tid = threadIdx.x, lane = tid & 63, w = tid >> 6;
    int quad = lane >> 4, l15 = lane & 15;
    int brow = b * 128;
    size_t base = (size_t)b * T_SEQ;

    // Q fragments (B-operand of swapped QK^T): Q[t=l15][h=kf*32+quad*8+i]
    f16x8 qfr[2][4];
    #pragma unroll
    for (int tt = 0; tt < 2; ++tt) {
        const f16_t* qt = q2 + (size_t)(brow + 2 * g + tt) * 2048 + l15 * 8;
        #pragma unroll
        for (int kf = 0; kf < 4; ++kf)
            qfr[tt][kf] = *(const f16x8*)(qt + (kf * 4 + quad) * 128);
    }

    f32x4 o[2][8] = {};   // [t-tile][h-tile of 16] accumulators

    // wave w processes s16-tiles j = c0*4+w, stepping by 4
    for (int j = c0 * 4 + w; j < c1 * 4; j += 4) {
        int s0 = j * 16;
        // K fragments (A-operand): K[s=l15][h=kf*32+quad*8+i]
        f16x8 kfr[4];
        const f16_t* kt = k2 + (size_t)(brow + j) * 2048 + l15 * 8;
        #pragma unroll
        for (int kf = 0; kf < 4; ++kf)
            kfr[kf] = *(const f16x8*)(kt + (kf * 4 + quad) * 128);

        // S^T tiles: D[row=s=quad*4+r][col=t=l15]
        f32x4 st[2] = {};
        #pragma unroll
        for (int tt = 0; tt < 2; ++tt)
            #pragma unroll
            for (int kf = 0; kf < 4; ++kf)
                st[tt] = __builtin_amdgcn_mfma_f32_16x16x32_f16(
                    kfr[kf], qfr[tt][kf], st[tt], 0, 0, 0);

        // P = exp(S)/colsum[s], in-register (A-frag of 16x16x16: m=t=l15,
        // k=s=quad*4+r)
        float4 cs = *(const float4*)&colsum[base + s0 + quad * 4];
        float iv0 = 1.0f / cs.x, iv1 = 1.0f / cs.y,
              iv2 = 1.0f / cs.z, iv3 = 1.0f / cs.w;
        int sg = s0 + quad * 4;
        f16x4 p[2];
        #pragma unroll
        for (int tt = 0; tt < 2; ++tt) {
            int t = trow + tt * 16 + l15;
            float p0 = (t >= sg + 0) ? __expf(st[tt][0]) * iv0 : 0.f;
            float p1 = (t >= sg + 1) ? __expf(st[tt][1]) * iv1 : 0.f;
            float p2 = (t >= sg + 2) ? __expf(st[tt][2]) * iv2 : 0.f;
            float p3 = (t >= sg + 3) ? __expf(st[tt][3]) * iv3 : 0.f;
            p[tt][0] = (f16_t)p0; p[tt][1] = (f16_t)p1;
            p[tt][2] = (f16_t)p2; p[tt][3] = (f16_t)p3;
        }

        // PV: B-frag V[s=quad*4+i][h=h8*16+l15] is 4 contiguous f16 in v2
        const f16_t* vt = v2 + ((size_t)(base + s0) >> 3) * 1024 +
                          (quad >> 1) * 1024 + (quad & 1) * 4;
        #pragma unroll
        for (int h8 = 0; h8 < 8; ++h8) {
            f16x4 vf = *(const f16x4*)&vt[(h8 * 16 + l15) * 8];
            o[0][h8] = __builtin_amdgcn_mfma_f32_16x16x16f16(p[0], vf, o[0][h8], 0, 0, 0);
            o[1][h8] = __builtin_amdgcn_mfma_f32_16x16x16f16(p[1], vf, o[1][h8], 0, 0, 0);
        }
    }

    // cross-wave reduce in LDS (4 barriers/block total), then one atomic pass
    #pragma unroll 1
    for (int wp = 0; wp < 4; ++wp) {
        if (w == wp) {
            #pragma unroll
            for (int tt = 0; tt < 2; ++tt)
                #pragma unroll
                for (int h8 = 0; h8 < 8; ++h8)
                    #pragma unroll
                    for (int r = 0; r < 4; ++r) {
                        int idx = (tt * 16 + quad * 4 + r) * 128 + h8 * 16 + l15;
                        if (wp == 0) Or[idx] = o[tt][h8][r];
                        else         Or[idx] += o[tt][h8][r];
                    }
        }
        __syncthreads();
    }
    float* ob = out + (base + trow) * HD;
    for (int idx = tid; idx < 32 * 128; idx += 256)
        atomicAdd(&ob[((idx >> 7)) * HD + (idx & 127)], Or[idx]);
}

// ---------------------------------------------------------------------------
extern "C" void kernel_launch(void* const* d_in, const int* in_sizes, int n_in,
                              void* d_out, int out_size, void* d_ws, size_t ws_size,
                              hipStream_t stream) {
    const float* X  = (const float*)d_in[0];
    const float* Wk = (const float*)d_in[1];
    const float* bk = (const float*)d_in[2];
    const float* Wq = (const float*)d_in[3];
    const float* bq = (const float*)d_in[4];
    const float* Wv = (const float*)d_in[5];
    const float* bv = (const float*)d_in[6];
    float* out = (float*)d_out;

    char* ws = (char*)d_ws;
    const size_t W2_B    = 24 * 16384 * 2;                   // 768 KiB
    const size_t BIAS_B  = 2048;
    const size_t QKV_B   = (size_t)NBATCH * T_SEQ * HD * 2;  // 4 MiB each
    f16_t* w2     = (f16_t*)ws;
    float* biasc  = (float*)(ws + W2_B);
    f16_t* q2     = (f16_t*)(ws + W2_B + BIAS_B);
    f16_t* k2     = (f16_t*)(ws + W2_B + BIAS_B + QKV_B);
    f16_t* v2     = (f16_t*)(ws + W2_B + BIAS_B + 2 * QKV_B);
    float* colsum = (float*)(ws + W2_B + BIAS_B + 3 * QKV_B);

    prep<<<dim3(2448), dim3(256), 0, stream>>>(Wk, bk, Wq, bq, Wv, bv, w2, biasc,
                                               (float4*)out, (float4*)colsum);
    qkv_gemm<<<dim3(768), dim3(256), 0, stream>>>(X, w2, biasc, q2, k2, v2);
    col_stats<<<dim3(1152), dim3(256), 0, stream>>>(q2, k2, colsum);
    attn_out<<<dim3(1280), dim3(256), 0, stream>>>(q2, k2, v2, colsum, out);
}

// Round 7
// 189.058 us; speedup vs baseline: 1.0496x; 1.0496x over previous
//
#include <hip/hip_runtime.h>
#include <hip/hip_bf16.h>

#define T_SEQ 2048
#define NBATCH 8
#define EMB 1024
#define HD 128

typedef _Float16 f16_t;
typedef _Float16 f16x8 __attribute__((ext_vector_type(8)));
typedef _Float16 f16x4 __attribute__((ext_vector_type(4)));
typedef float f32x4 __attribute__((ext_vector_type(4)));

// Tiled layouts — every MFMA fragment load is 16B/lane dense:
//  q2/k2 : [tt=row/16][hc=h/8(16)][r16=row%16][8]   idx = tt*2048 + hc*128 + r16*8 + h%8
//  v2    : [sc=row/8][h(128)][8]                    idx = sc*1024 + h*8 + row%8
//  w2    : [ntile=n/16(24)][kc8=k/8(128)][r16=n%16][8]
// No softmax max-subtraction (|S|<~4, exp fp32-safe; validated prior session).
// R4 lesson: per-lane scattered A-fragment loads (4KB row stride) are ~8x the
// VMEM transactions of 4-lanes-per-row staging -> keep A staged.
// R6 lesson: swapped-QK^T attn_out regressed (serial per-wave chain + serial
// Or-reduce tail); reverted to verified version. qkv is barrier-drain gated
// at 3 lockstep blocks/CU -> v5 uses 64x64 tiles (6 blocks/CU) so other
// blocks' compute covers each block's barrier drain (m114 mechanism).

// async global->LDS, 16B per lane
__device__ __forceinline__ void g2l(const f16_t* g, f16_t* l) {
    __builtin_amdgcn_global_load_lds(
        (const __attribute__((address_space(1))) unsigned int*)g,
        (__attribute__((address_space(3))) unsigned int*)l, 16, 0, 0);
}

// ---------------------------------------------------------------------------
// Kernel 1: fused prep (unchanged from R0-verified).
// ---------------------------------------------------------------------------
__global__ __launch_bounds__(256) void prep(
    const float* __restrict__ Wk, const float* __restrict__ bk,
    const float* __restrict__ Wq, const float* __restrict__ bq,
    const float* __restrict__ Wv, const float* __restrict__ bv,
    f16_t* __restrict__ w2, float* __restrict__ biasc,
    float4* __restrict__ out4, float4* __restrict__ colsum4) {
    int bid = blockIdx.x;
    int t = threadIdx.x;
    if (bid < 384) {
        int n = bid;
        const float scale = 0.08838834764831845f;  // HEAD^-0.5
        const float* W; const float* bias; float sc; int col;
        if (n < 128)      { W = Wq; bias = bq; sc = scale; col = n; }
        else if (n < 256) { W = Wk; bias = bk; sc = 1.0f;  col = n - 128; }
        else              { W = Wv; bias = bv; sc = 1.0f;  col = n - 256; }
        if (t < 128) {
            int k0 = t * 8;
            f16x8 v;
            #pragma unroll
            for (int i = 0; i < 8; ++i) v[i] = (f16_t)(W[(size_t)(k0 + i) * HD + col] * sc);
            *(f16x8*)&w2[(size_t)(n >> 4) * 16384 + (size_t)(k0 >> 3) * 128 + (n & 15) * 8] = v;
        }
        if (t == 0) biasc[n] = bias[col] * sc;
    } else if (bid < 384 + 2048) {
        out4[(size_t)(bid - 384) * 256 + t] = make_float4(0.f, 0.f, 0.f, 0.f);
    } else {
        colsum4[(size_t)(bid - 2432) * 256 + t] = make_float4(0.f, 0.f, 0.f, 0.f);
    }
}

// ---------------------------------------------------------------------------
// Kernel 2 (v5): 64x64 tiles -> 1536 blocks = 6 blocks/CU. Only Xs in LDS
// (dbuf 18KB); B fragments read direct from L2-resident w2 (R0-verified
// pattern). One barrier/chunk; barrier drains covered by 5 other resident
// blocks. Wave = 32x32 sub-tile, acc[2][2].
// ---------------------------------------------------------------------------
__global__ __launch_bounds__(256, 6) void qkv_gemm(
    const float* __restrict__ X, const f16_t* __restrict__ w2,
    const float* __restrict__ biasc,
    f16_t* __restrict__ q2, f16_t* __restrict__ k2, f16_t* __restrict__ v2) {
    __shared__ f16_t Xs[2][64 * 72];

    int bid = blockIdx.x;
    int r8 = bid & 7, g = bid >> 3;          // g in [0,192)
    int band = (g / 6) * 8 + r8;             // [0,256), XCD-affine
    int n0 = (g % 6) * 64;
    int m0 = band * 64;
    int tid = threadIdx.x;
    int lane = tid & 63, w = tid >> 6;
    int quad = lane >> 4, l15 = lane & 15;
    int msub = (w & 1) * 32, nsub = (w >> 1) * 32;

    int srow = tid >> 2;           // 0..63
    int scg  = (tid & 3) * 16;     // 16-float group within BK=64

    const float* xrow = X + (size_t)(m0 + srow) * EMB + scg;
    int ntbase = (n0 >> 4) + (nsub >> 4);

    f32x4 acc[2][2] = {};
    float4 pf[4];

    auto loadA = [&](int kc) {
        #pragma unroll
        for (int u = 0; u < 4; ++u) pf[u] = *(const float4*)(xrow + kc * 64 + u * 4);
    };
    auto stageA = [&](int buf) {
        union { f16_t h[8]; uint4 u4; } p0, p1;
        p0.h[0] = (f16_t)pf[0].x; p0.h[1] = (f16_t)pf[0].y;
        p0.h[2] = (f16_t)pf[0].z; p0.h[3] = (f16_t)pf[0].w;
        p0.h[4] = (f16_t)pf[1].x; p0.h[5] = (f16_t)pf[1].y;
        p0.h[6] = (f16_t)pf[1].z; p0.h[7] = (f16_t)pf[1].w;
        p1.h[0] = (f16_t)pf[2].x; p1.h[1] = (f16_t)pf[2].y;
        p1.h[2] = (f16_t)pf[2].z; p1.h[3] = (f16_t)pf[2].w;
        p1.h[4] = (f16_t)pf[3].x; p1.h[5] = (f16_t)pf[3].y;
        p1.h[6] = (f16_t)pf[3].z; p1.h[7] = (f16_t)pf[3].w;
        *(uint4*)&Xs[buf][srow * 72 + scg] = p0.u4;
        *(uint4*)&Xs[buf][srow * 72 + scg + 8] = p1.u4;
    };
    auto compute = [&](int kc, int buf) {
        #pragma unroll
        for (int ks = 0; ks < 2; ++ks) {
            f16x8 afr0 = *(const f16x8*)&Xs[buf][(msub + l15) * 72 + ks * 32 + quad * 8];
            f16x8 afr1 = *(const f16x8*)&Xs[buf][(msub + 16 + l15) * 72 + ks * 32 + quad * 8];
            #pragma unroll
            for (int nf = 0; nf < 2; ++nf) {
                f16x8 bfr = *(const f16x8*)&w2[(size_t)(ntbase + nf) * 16384 +
                    (size_t)(kc * 8 + ks * 4 + quad) * 128 + l15 * 8];
                acc[0][nf] = __builtin_amdgcn_mfma_f32_16x16x32_f16(afr0, bfr, acc[0][nf], 0, 0, 0);
                acc[1][nf] = __builtin_amdgcn_mfma_f32_16x16x32_f16(afr1, bfr, acc[1][nf], 0, 0, 0);
            }
        }
    };

    // prologue: fill buffer 0
    loadA(0);
    stageA(0);
    __syncthreads();

    for (int kc = 0; kc < 16; ++kc) {
        int cur = kc & 1;
        if (kc + 1 < 16) loadA(kc + 1);
        compute(kc, cur);
        if (kc + 1 < 16) stageA(cur ^ 1);
        __syncthreads();
    }

    // epilogue -> tiled layouts
    #pragma unroll
    for (int nf = 0; nf < 2; ++nf) {
        int ng = n0 + nsub + nf * 16 + l15;
        float bval = biasc[ng];
        #pragma unroll
        for (int mf = 0; mf < 2; ++mf) {
            int rowg = m0 + msub + mf * 16 + quad * 4;
            f32x4 a = acc[mf][nf];
            if (ng < 256) {
                f16_t* dst = (ng < 128) ? q2 : k2;
                int c = ng & 127;
                #pragma unroll
                for (int r = 0; r < 4; ++r) {
                    int row = rowg + r;
                    dst[(size_t)(row >> 4) * 2048 + (c >> 3) * 128 + (row & 15) * 8 + (c & 7)]
                        = (f16_t)(a[r] + bval);
                }
            } else {
                int h = ng - 256;
                f16x4 hv;
                #pragma unroll
                for (int r = 0; r < 4; ++r) hv[r] = (f16_t)(a[r] + bval);
                *(f16x4*)&v2[(size_t)(rowg >> 3) * 1024 + h * 8 + (rowg & 7)] = hv;
            }
        }
    }
}

// ---------------------------------------------------------------------------
// Kernel 3: column sums — R4 v2 (barrier-free, direct L2 reads). Unchanged.
// ---------------------------------------------------------------------------
__global__ __launch_bounds__(256, 4) void col_stats(
    const f16_t* __restrict__ q2, const f16_t* __restrict__ k2,
    float* __restrict__ colsum) {
    int bid = blockIdx.x;
    int b = bid & 7;
    int item = 143 - (bid >> 3);
    int cg = 0, slab = 0, cum = 0;
    for (int c = 0; c < 32; ++c) {
        int n = (32 - c + 3) >> 2;
        if (item < cum + n) { cg = c; slab = item - cum; break; }
        cum += n;
    }
    int tc0 = cg + slab * 4, tc1 = min(tc0 + 4, 32);

    int tid = threadIdx.x, lane = tid & 63, w = tid >> 6;
    int quad = lane >> 4, l15 = lane & 15;
    int brow = b * 128;
    size_t base = (size_t)b * T_SEQ;

    f16x8 bfrs[4][4];
    #pragma unroll
    for (int st = 0; st < 4; ++st) {
        const f16_t* kt = k2 + (size_t)(brow + cg * 4 + st) * 2048 + l15 * 8;
        #pragma unroll
        for (int kf = 0; kf < 4; ++kf)
            bfrs[st][kf] = *(const f16x8*)(kt + (kf * 4 + quad) * 128);
    }

    float lacc[4] = {0.f, 0.f, 0.f, 0.f};

    for (int tc = tc0; tc < tc1; ++tc) {
        int tb = tc * 64;
        f16x8 afr[4];
        const f16_t* qt = q2 + (size_t)(brow + tc * 4 + w) * 2048 + l15 * 8;
        #pragma unroll
        for (int kf = 0; kf < 4; ++kf)
            afr[kf] = *(const f16x8*)(qt + (kf * 4 + quad) * 128);
        #pragma unroll
        for (int st = 0; st < 4; ++st) {
            f32x4 s = {};
            #pragma unroll
            for (int kf = 0; kf < 4; ++kf)
                s = __builtin_amdgcn_mfma_f32_16x16x32_f16(afr[kf], bfrs[st][kf], s, 0, 0, 0);
            int scol = cg * 64 + st * 16 + l15;
            #pragma unroll
            for (int r = 0; r < 4; ++r) {
                int t = tb + w * 16 + quad * 4 + r;
                if (t >= scol) lacc[st] += __expf(s[r]);
            }
        }
    }

    #pragma unroll
    for (int st = 0; st < 4; ++st) {
        float v = lacc[st];
        v += __shfl_xor(v, 16, 64);
        v += __shfl_xor(v, 32, 64);
        if (quad == 0) atomicAdd(&colsum[base + cg * 64 + st * 16 + l15], v);
    }
}

// ---------------------------------------------------------------------------
// Kernel 4: output pass — REVERTED to R0-verified version (Kl/Vl/Pl staged).
// ---------------------------------------------------------------------------
__global__ __launch_bounds__(256, 4) void attn_out(
    const f16_t* __restrict__ q2, const f16_t* __restrict__ k2,
    const f16_t* __restrict__ v2, const float* __restrict__ colsum,
    float* __restrict__ out) {
    __shared__ __align__(16) f16_t Kl[4 * 2048];
    __shared__ __align__(16) f16_t Vl[8 * 1024];
    __shared__ __align__(16) f16_t Pl[32 * 72];

    int bid = blockIdx.x;
    int b = bid & 7;
    int item = 159 - (bid >> 3);
    int g = 0, slab = 0, cum = 0;
    for (int gg = 0; gg < 64; ++gg) {
        int n = (((gg >> 1) + 1) + 7) >> 3;
        if (item < cum + n) { g = gg; slab = item - cum; break; }
        cum += n;
    }
    int nch = (g >> 1) + 1;
    int c0 = slab * 8, c1 = min(c0 + 8, nch);
    int trow = g * 32;

    int tid = threadIdx.x, lane = tid & 63, w = tid >> 6;
    int quad = lane >> 4, l15 = lane & 15;
    int brow = b * 128;
    size_t base = (size_t)b * T_SEQ;

    f16x8 qfr[2][4];
    #pragma unroll
    for (int tt = 0; tt < 2; ++tt) {
        const f16_t* qt = q2 + (size_t)(brow + 2 * g + tt) * 2048 + l15 * 8;
        #pragma unroll
        for (int kf = 0; kf < 4; ++kf)
            qfr[tt][kf] = *(const f16x8*)(qt + (kf * 4 + quad) * 128);
    }

    f32x4 o[2][2] = {};

    for (int c = c0; c < c1; ++c) {
        int sb = c * 64;
        __syncthreads();
        const f16_t* ksrc = k2 + (size_t)(brow + (sb >> 4)) * 2048;
        const f16_t* vsrc = v2 + (((size_t)base + sb) >> 3) * 1024;
        #pragma unroll
        for (int i = 0; i < 4; ++i) {
            g2l(ksrc + i * 2048 + tid * 8, Kl + i * 2048 + tid * 8);
            g2l(vsrc + i * 2048 + tid * 8, Vl + i * 2048 + tid * 8);
        }
        __syncthreads();

        float iv = 1.0f / colsum[base + sb + w * 16 + l15];
        int scol = sb + w * 16 + l15;
        f16x8 bfr[4];
        #pragma unroll
        for (int kf = 0; kf < 4; ++kf)
            bfr[kf] = *(const f16x8*)&Kl[w * 2048 + (kf * 4 + quad) * 128 + l15 * 8];
        #pragma unroll
        for (int tt = 0; tt < 2; ++tt) {
            f32x4 s = {};
            #pragma unroll
            for (int kf = 0; kf < 4; ++kf)
                s = __builtin_amdgcn_mfma_f32_16x16x32_f16(qfr[tt][kf], bfr[kf], s, 0, 0, 0);
            #pragma unroll
            for (int r = 0; r < 4; ++r) {
                int t = trow + tt * 16 + quad * 4 + r;
                float pv = (t >= scol) ? __expf(s[r]) * iv : 0.f;
                Pl[(tt * 16 + quad * 4 + r) * 72 + w * 16 + l15] = (f16_t)pv;
            }
        }
        __syncthreads();

        #pragma unroll
        for (int kf2 = 0; kf2 < 2; ++kf2) {
            f16x8 pa0 = *(const f16x8*)&Pl[(l15) * 72 + kf2 * 32 + quad * 8];
            f16x8 pa1 = *(const f16x8*)&Pl[(16 + l15) * 72 + kf2 * 32 + quad * 8];
            #pragma unroll
            for (int hh = 0; hh < 2; ++hh) {
                f16x8 vfr = *(const f16x8*)&Vl[(kf2 * 4 + quad) * 1024 + (w * 32 + hh * 16 + l15) * 8];
                o[0][hh] = __builtin_amdgcn_mfma_f32_16x16x32_f16(pa0, vfr, o[0][hh], 0, 0, 0);
                o[1][hh] = __builtin_amdgcn_mfma_f32_16x16x32_f16(pa1, vfr, o[1][hh], 0, 0, 0);
            }
        }
    }

    #pragma unroll
    for (int tt = 0; tt < 2; ++tt)
        #pragma unroll
        for (int hh = 0; hh < 2; ++hh)
            #pragma unroll
            for (int r = 0; r < 4; ++r)
                atomicAdd(&out[(base + trow + tt * 16 + quad * 4 + r) * HD + w * 32 + hh * 16 + l15],
                          o[tt][hh][r]);
}

// ---------------------------------------------------------------------------
extern "C" void kernel_launch(void* const* d_in, const int* in_sizes, int n_in,
                              void* d_out, int out_size, void* d_ws, size_t ws_size,
                              hipStream_t stream) {
    const float* X  = (const float*)d_in[0];
    const float* Wk = (const float*)d_in[1];
    const float* bk = (const float*)d_in[2];
    const float* Wq = (const float*)d_in[3];
    const float* bq = (const float*)d_in[4];
    const float* Wv = (const float*)d_in[5];
    const float* bv = (const float*)d_in[6];
    float* out = (float*)d_out;

    char* ws = (char*)d_ws;
    const size_t W2_B    = 24 * 16384 * 2;                   // 768 KiB
    const size_t BIAS_B  = 2048;
    const size_t QKV_B   = (size_t)NBATCH * T_SEQ * HD * 2;  // 4 MiB each
    f16_t* w2     = (f16_t*)ws;
    float* biasc  = (float*)(ws + W2_B);
    f16_t* q2     = (f16_t*)(ws + W2_B + BIAS_B);
    f16_t* k2     = (f16_t*)(ws + W2_B + BIAS_B + QKV_B);
    f16_t* v2     = (f16_t*)(ws + W2_B + BIAS_B + 2 * QKV_B);
    float* colsum = (float*)(ws + W2_B + BIAS_B + 3 * QKV_B);

    prep<<<dim3(2448), dim3(256), 0, stream>>>(Wk, bk, Wq, bq, Wv, bv, w2, biasc,
                                               (float4*)out, (float4*)colsum);
    qkv_gemm<<<dim3(1536), dim3(256), 0, stream>>>(X, w2, biasc, q2, k2, v2);
    col_stats<<<dim3(1152), dim3(256), 0, stream>>>(q2, k2, colsum);
    attn_out<<<dim3(1280), dim3(256), 0, stream>>>(q2, k2, v2, colsum, out);
}

// Round 8
// 177.598 us; speedup vs baseline: 1.1174x; 1.0645x over previous
//
#include <hip/hip_runtime.h>
#include <hip/hip_bf16.h>

#define T_SEQ 2048
#define NBATCH 8
#define EMB 1024
#define HD 128

typedef _Float16 f16_t;
typedef _Float16 f16x8 __attribute__((ext_vector_type(8)));
typedef _Float16 f16x4 __attribute__((ext_vector_type(4)));
typedef float f32x4 __attribute__((ext_vector_type(4)));

// Tiled layouts — every MFMA fragment load is 16B/lane dense:
//  q2/k2 : [tt=row/16][hc=h/8(16)][r16=row%16][8]   idx = tt*2048 + hc*128 + r16*8 + h%8
//  v2    : [sc=row/8][h(128)][8]                    idx = sc*1024 + h*8 + row%8
//  w2    : [ntile=n/16(24)][kc8=k/8(128)][r16=n%16][8]
// No softmax max-subtraction (|S|<~4, exp fp32-safe; validated prior session).
// R4 lesson: per-lane scattered A-fragment loads -> 8x VMEM transactions; keep A staged.
// R7 lesson: n-split>3 doubles A traffic/CU (the scarce stream); 64x64 tiles regress.
// R8: consolidation — all kernels at best-verified form; out/colsum zeroing moved
// to hipMemsetAsync (stream-ordered, capture-safe); prep = w2 pack only.

// async global->LDS, 16B per lane
__device__ __forceinline__ void g2l(const f16_t* g, f16_t* l) {
    __builtin_amdgcn_global_load_lds(
        (const __attribute__((address_space(1))) unsigned int*)g,
        (__attribute__((address_space(3))) unsigned int*)l, 16, 0, 0);
}

// ---------------------------------------------------------------------------
// Kernel 1: prep — w2 pack + scaled biases only (zeroing now via memset).
// ---------------------------------------------------------------------------
__global__ __launch_bounds__(256) void prep(
    const float* __restrict__ Wk, const float* __restrict__ bk,
    const float* __restrict__ Wq, const float* __restrict__ bq,
    const float* __restrict__ Wv, const float* __restrict__ bv,
    f16_t* __restrict__ w2, float* __restrict__ biasc) {
    int n = blockIdx.x;
    int t = threadIdx.x;
    const float scale = 0.08838834764831845f;  // HEAD^-0.5
    const float* W; const float* bias; float sc; int col;
    if (n < 128)      { W = Wq; bias = bq; sc = scale; col = n; }
    else if (n < 256) { W = Wk; bias = bk; sc = 1.0f;  col = n - 128; }
    else              { W = Wv; bias = bv; sc = 1.0f;  col = n - 256; }
    if (t < 128) {
        int k0 = t * 8;
        f16x8 v;
        #pragma unroll
        for (int i = 0; i < 8; ++i) v[i] = (f16_t)(W[(size_t)(k0 + i) * HD + col] * sc);
        *(f16x8*)&w2[(size_t)(n >> 4) * 16384 + (size_t)(k0 >> 3) * 128 + (n & 15) * 8] = v;
    }
    if (t == 0) biasc[n] = bias[col] * sc;
}

// ---------------------------------------------------------------------------
// Kernel 2: QKV GEMM — EXACT R3 v3 (43.0us verified best). 768 blocks,
// 64x128 tiles, A staged coalesced (4 lanes/row), B LDS double-buffered via
// g2l, single barrier per chunk.
// ---------------------------------------------------------------------------
__global__ __launch_bounds__(256) void qkv_gemm(
    const float* __restrict__ X, const f16_t* __restrict__ w2,
    const float* __restrict__ biasc,
    f16_t* __restrict__ q2, f16_t* __restrict__ k2, f16_t* __restrict__ v2) {
    __shared__ f16_t Xs[2][64 * 72];
    __shared__ __align__(16) f16_t Bl[2][8 * 1024];

    int bid = blockIdx.x;
    int r8 = bid & 7, g = bid >> 3;
    int band = (g / 3) * 8 + r8;             // 64-row band, XCD-affine
    int i = g % 3;
    int m0 = band * 64, n0 = i * 128;
    int tid = threadIdx.x;
    int lane = tid & 63, w = tid >> 6;
    int quad = lane >> 4, l15 = lane & 15;
    int msub = (w & 1) * 32, nsub = (w >> 1) * 64;

    int srow = tid >> 2;           // 0..63
    int scg  = (tid & 3) * 16;     // 16-float group within BK=64

    const float* xrow = X + (size_t)(m0 + srow) * EMB + scg;
    const f16_t* bbase = w2 + (size_t)(n0 >> 4) * 16384;

    f32x4 acc[2][4] = {};
    float4 pf[4];

    auto loadA = [&](int kc) {
        #pragma unroll
        for (int u = 0; u < 4; ++u) pf[u] = *(const float4*)(xrow + kc * 64 + u * 4);
    };
    auto stageB = [&](int kc, int buf) {
        const f16_t* bsrc = bbase + (size_t)kc * 1024;
        #pragma unroll
        for (int ii = 0; ii < 4; ++ii) {
            int D = tid * 16 + ii * 4096;                 // byte offset in 16KB
            g2l(bsrc + (size_t)(D >> 11) * 16384 + ((D & 2047) >> 1),
                &Bl[buf][D >> 1]);
        }
    };
    auto stageA = [&](int buf) {
        union { f16_t h[8]; uint4 u4; } p0, p1;
        p0.h[0] = (f16_t)pf[0].x; p0.h[1] = (f16_t)pf[0].y;
        p0.h[2] = (f16_t)pf[0].z; p0.h[3] = (f16_t)pf[0].w;
        p0.h[4] = (f16_t)pf[1].x; p0.h[5] = (f16_t)pf[1].y;
        p0.h[6] = (f16_t)pf[1].z; p0.h[7] = (f16_t)pf[1].w;
        p1.h[0] = (f16_t)pf[2].x; p1.h[1] = (f16_t)pf[2].y;
        p1.h[2] = (f16_t)pf[2].z; p1.h[3] = (f16_t)pf[2].w;
        p1.h[4] = (f16_t)pf[3].x; p1.h[5] = (f16_t)pf[3].y;
        p1.h[6] = (f16_t)pf[3].z; p1.h[7] = (f16_t)pf[3].w;
        *(uint4*)&Xs[buf][srow * 72 + scg] = p0.u4;
        *(uint4*)&Xs[buf][srow * 72 + scg + 8] = p1.u4;
    };
    auto compute = [&](int buf) {
        #pragma unroll
        for (int ks = 0; ks < 2; ++ks) {
            f16x8 afr0 = *(const f16x8*)&Xs[buf][(msub + l15) * 72 + ks * 32 + quad * 8];
            f16x8 afr1 = *(const f16x8*)&Xs[buf][(msub + 16 + l15) * 72 + ks * 32 + quad * 8];
            #pragma unroll
            for (int nf = 0; nf < 4; ++nf) {
                int ntl = (nsub >> 4) + nf;
                f16x8 bfr = *(const f16x8*)&Bl[buf][ntl * 1024 + (ks * 4 + quad) * 128 + l15 * 8];
                acc[0][nf] = __builtin_amdgcn_mfma_f32_16x16x32_f16(afr0, bfr, acc[0][nf], 0, 0, 0);
                acc[1][nf] = __builtin_amdgcn_mfma_f32_16x16x32_f16(afr1, bfr, acc[1][nf], 0, 0, 0);
            }
        }
    };

    // prologue: fill buffer 0
    loadA(0);
    stageB(0, 0);
    stageA(0);
    __syncthreads();

    for (int kc = 0; kc < 16; ++kc) {
        int cur = kc & 1, nxt = cur ^ 1;
        if (kc + 1 < 16) {
            loadA(kc + 1);
            stageB(kc + 1, nxt);
        }
        compute(cur);
        if (kc + 1 < 16) stageA(nxt);
        __syncthreads();
    }

    // epilogue -> tiled layouts
    #pragma unroll
    for (int nf = 0; nf < 4; ++nf) {
        int ng = n0 + nsub + nf * 16 + l15;
        float bval = biasc[ng];
        #pragma unroll
        for (int mf = 0; mf < 2; ++mf) {
            int rowg = m0 + msub + mf * 16 + quad * 4;
            f32x4 a = acc[mf][nf];
            if (ng < 256) {
                f16_t* dst = (ng < 128) ? q2 : k2;
                int c = ng & 127;
                #pragma unroll
                for (int r = 0; r < 4; ++r) {
                    int row = rowg + r;
                    dst[(size_t)(row >> 4) * 2048 + (c >> 3) * 128 + (row & 15) * 8 + (c & 7)]
                        = (f16_t)(a[r] + bval);
                }
            } else {
                int h = ng - 256;
                f16x4 hv;
                #pragma unroll
                for (int r = 0; r < 4; ++r) hv[r] = (f16_t)(a[r] + bval);
                *(f16x4*)&v2[(size_t)(rowg >> 3) * 1024 + h * 8 + (rowg & 7)] = hv;
            }
        }
    }
}

// ---------------------------------------------------------------------------
// Kernel 3: column sums — R4 v2 (barrier-free, direct L2 reads). Verified.
// ---------------------------------------------------------------------------
__global__ __launch_bounds__(256, 4) void col_stats(
    const f16_t* __restrict__ q2, const f16_t* __restrict__ k2,
    float* __restrict__ colsum) {
    int bid = blockIdx.x;
    int b = bid & 7;
    int item = 143 - (bid >> 3);
    int cg = 0, slab = 0, cum = 0;
    for (int c = 0; c < 32; ++c) {
        int n = (32 - c + 3) >> 2;
        if (item < cum + n) { cg = c; slab = item - cum; break; }
        cum += n;
    }
    int tc0 = cg + slab * 4, tc1 = min(tc0 + 4, 32);

    int tid = threadIdx.x, lane = tid & 63, w = tid >> 6;
    int quad = lane >> 4, l15 = lane & 15;
    int brow = b * 128;
    size_t base = (size_t)b * T_SEQ;

    f16x8 bfrs[4][4];
    #pragma unroll
    for (int st = 0; st < 4; ++st) {
        const f16_t* kt = k2 + (size_t)(brow + cg * 4 + st) * 2048 + l15 * 8;
        #pragma unroll
        for (int kf = 0; kf < 4; ++kf)
            bfrs[st][kf] = *(const f16x8*)(kt + (kf * 4 + quad) * 128);
    }

    float lacc[4] = {0.f, 0.f, 0.f, 0.f};

    for (int tc = tc0; tc < tc1; ++tc) {
        int tb = tc * 64;
        f16x8 afr[4];
        const f16_t* qt = q2 + (size_t)(brow + tc * 4 + w) * 2048 + l15 * 8;
        #pragma unroll
        for (int kf = 0; kf < 4; ++kf)
            afr[kf] = *(const f16x8*)(qt + (kf * 4 + quad) * 128);
        #pragma unroll
        for (int st = 0; st < 4; ++st) {
            f32x4 s = {};
            #pragma unroll
            for (int kf = 0; kf < 4; ++kf)
                s = __builtin_amdgcn_mfma_f32_16x16x32_f16(afr[kf], bfrs[st][kf], s, 0, 0, 0);
            int scol = cg * 64 + st * 16 + l15;
            #pragma unroll
            for (int r = 0; r < 4; ++r) {
                int t = tb + w * 16 + quad * 4 + r;
                if (t >= scol) lacc[st] += __expf(s[r]);
            }
        }
    }

    #pragma unroll
    for (int st = 0; st < 4; ++st) {
        float v = lacc[st];
        v += __shfl_xor(v, 16, 64);
        v += __shfl_xor(v, 32, 64);
        if (quad == 0) atomicAdd(&colsum[base + cg * 64 + st * 16 + l15], v);
    }
}

// ---------------------------------------------------------------------------
// Kernel 4: output pass — EXACT R0-verified version (Kl/Vl/Pl staged).
// ---------------------------------------------------------------------------
__global__ __launch_bounds__(256, 4) void attn_out(
    const f16_t* __restrict__ q2, const f16_t* __restrict__ k2,
    const f16_t* __restrict__ v2, const float* __restrict__ colsum,
    float* __restrict__ out) {
    __shared__ __align__(16) f16_t Kl[4 * 2048];
    __shared__ __align__(16) f16_t Vl[8 * 1024];
    __shared__ __align__(16) f16_t Pl[32 * 72];

    int bid = blockIdx.x;
    int b = bid & 7;
    int item = 159 - (bid >> 3);
    int g = 0, slab = 0, cum = 0;
    for (int gg = 0; gg < 64; ++gg) {
        int n = (((gg >> 1) + 1) + 7) >> 3;
        if (item < cum + n) { g = gg; slab = item - cum; break; }
        cum += n;
    }
    int nch = (g >> 1) + 1;
    int c0 = slab * 8, c1 = min(c0 + 8, nch);
    int trow = g * 32;

    int tid = threadIdx.x, lane = tid & 63, w = tid >> 6;
    int quad = lane >> 4, l15 = lane & 15;
    int brow = b * 128;
    size_t base = (size_t)b * T_SEQ;

    f16x8 qfr[2][4];
    #pragma unroll
    for (int tt = 0; tt < 2; ++tt) {
        const f16_t* qt = q2 + (size_t)(brow + 2 * g + tt) * 2048 + l15 * 8;
        #pragma unroll
        for (int kf = 0; kf < 4; ++kf)
            qfr[tt][kf] = *(const f16x8*)(qt + (kf * 4 + quad) * 128);
    }

    f32x4 o[2][2] = {};

    for (int c = c0; c < c1; ++c) {
        int sb = c * 64;
        __syncthreads();
        const f16_t* ksrc = k2 + (size_t)(brow + (sb >> 4)) * 2048;
        const f16_t* vsrc = v2 + (((size_t)base + sb) >> 3) * 1024;
        #pragma unroll
        for (int i = 0; i < 4; ++i) {
            g2l(ksrc + i * 2048 + tid * 8, Kl + i * 2048 + tid * 8);
            g2l(vsrc + i * 2048 + tid * 8, Vl + i * 2048 + tid * 8);
        }
        __syncthreads();

        float iv = 1.0f / colsum[base + sb + w * 16 + l15];
        int scol = sb + w * 16 + l15;
        f16x8 bfr[4];
        #pragma unroll
        for (int kf = 0; kf < 4; ++kf)
            bfr[kf] = *(const f16x8*)&Kl[w * 2048 + (kf * 4 + quad) * 128 + l15 * 8];
        #pragma unroll
        for (int tt = 0; tt < 2; ++tt) {
            f32x4 s = {};
            #pragma unroll
            for (int kf = 0; kf < 4; ++kf)
                s = __builtin_amdgcn_mfma_f32_16x16x32_f16(qfr[tt][kf], bfr[kf], s, 0, 0, 0);
            #pragma unroll
            for (int r = 0; r < 4; ++r) {
                int t = trow + tt * 16 + quad * 4 + r;
                float pv = (t >= scol) ? __expf(s[r]) * iv : 0.f;
                Pl[(tt * 16 + quad * 4 + r) * 72 + w * 16 + l15] = (f16_t)pv;
            }
        }
        __syncthreads();

        #pragma unroll
        for (int kf2 = 0; kf2 < 2; ++kf2) {
            f16x8 pa0 = *(const f16x8*)&Pl[(l15) * 72 + kf2 * 32 + quad * 8];
            f16x8 pa1 = *(const f16x8*)&Pl[(16 + l15) * 72 + kf2 * 32 + quad * 8];
            #pragma unroll
            for (int hh = 0; hh < 2; ++hh) {
                f16x8 vfr = *(const f16x8*)&Vl[(kf2 * 4 + quad) * 1024 + (w * 32 + hh * 16 + l15) * 8];
                o[0][hh] = __builtin_amdgcn_mfma_f32_16x16x32_f16(pa0, vfr, o[0][hh], 0, 0, 0);
                o[1][hh] = __builtin_amdgcn_mfma_f32_16x16x32_f16(pa1, vfr, o[1][hh], 0, 0, 0);
            }
        }
    }

    #pragma unroll
    for (int tt = 0; tt < 2; ++tt)
        #pragma unroll
        for (int hh = 0; hh < 2; ++hh)
            #pragma unroll
            for (int r = 0; r < 4; ++r)
                atomicAdd(&out[(base + trow + tt * 16 + quad * 4 + r) * HD + w * 32 + hh * 16 + l15],
                          o[tt][hh][r]);
}

// ---------------------------------------------------------------------------
extern "C" void kernel_launch(void* const* d_in, const int* in_sizes, int n_in,
                              void* d_out, int out_size, void* d_ws, size_t ws_size,
                              hipStream_t stream) {
    const float* X  = (const float*)d_in[0];
    const float* Wk = (const float*)d_in[1];
    const float* bk = (const float*)d_in[2];
    const float* Wq = (const float*)d_in[3];
    const float* bq = (const float*)d_in[4];
    const float* Wv = (const float*)d_in[5];
    const float* bv = (const float*)d_in[6];
    float* out = (float*)d_out;

    char* ws = (char*)d_ws;
    const size_t W2_B    = 24 * 16384 * 2;                   // 768 KiB
    const size_t BIAS_B  = 2048;
    const size_t QKV_B   = (size_t)NBATCH * T_SEQ * HD * 2;  // 4 MiB each
    f16_t* w2     = (f16_t*)ws;
    float* biasc  = (float*)(ws + W2_B);
    f16_t* q2     = (f16_t*)(ws + W2_B + BIAS_B);
    f16_t* k2     = (f16_t*)(ws + W2_B + BIAS_B + QKV_B);
    f16_t* v2     = (f16_t*)(ws + W2_B + BIAS_B + 2 * QKV_B);
    float* colsum = (float*)(ws + W2_B + BIAS_B + 3 * QKV_B);

    // zero out (8MB) + colsum (64KB) via stream-ordered memsets (capture-safe)
    hipMemsetAsync(out, 0, (size_t)NBATCH * T_SEQ * HD * sizeof(float), stream);
    hipMemsetAsync(colsum, 0, (size_t)NBATCH * T_SEQ * sizeof(float), stream);

    prep<<<dim3(384), dim3(256), 0, stream>>>(Wk, bk, Wq, bq, Wv, bv, w2, biasc);
    qkv_gemm<<<dim3(768), dim3(256), 0, stream>>>(X, w2, biasc, q2, k2, v2);
    col_stats<<<dim3(1152), dim3(256), 0, stream>>>(q2, k2, colsum);
    attn_out<<<dim3(1280), dim3(256), 0, stream>>>(q2, k2, v2, colsum, out);
}

// Round 9
// 174.043 us; speedup vs baseline: 1.1402x; 1.0204x over previous
//
#include <hip/hip_runtime.h>
#include <hip/hip_bf16.h>

#define T_SEQ 2048
#define NBATCH 8
#define EMB 1024
#define HD 128

typedef _Float16 f16_t;
typedef _Float16 f16x8 __attribute__((ext_vector_type(8)));
typedef _Float16 f16x4 __attribute__((ext_vector_type(4)));
typedef float f32x4 __attribute__((ext_vector_type(4)));

// Tiled layouts — every MFMA fragment load is 16B/lane dense:
//  q2/k2 : [tt=row/16][hc=h/8(16)][r16=row%16][8]   idx = tt*2048 + hc*128 + r16*8 + h%8
//  v2    : [sc=row/8][h(128)][8]                    idx = sc*1024 + h*8 + row%8
//  w2    : [ntile=n/16(24)][kc8=k/8(128)][r16=n%16][8]
// No softmax max-subtraction (|S|<~4, exp fp32-safe; validated prior session).
// R4 lesson: per-lane scattered A-frag loads -> 8x VMEM transactions; keep A staged.
// R7 lesson: n-split>3 doubles A traffic/CU; 64x64 qkv tiles regress.
// R9: attn_out v4 — K/V direct to regs (K wave-private, V via L2), Pl double-
// buffered -> ONE barrier per chunk whose drain set is already-consumed loads;
// prefetch for c+1 issued AFTER the barrier (covered by PV(c)'s MFMAs), since
// any load issued before __syncthreads gets fully drained by vmcnt(0).

// async global->LDS, 16B per lane
__device__ __forceinline__ void g2l(const f16_t* g, f16_t* l) {
    __builtin_amdgcn_global_load_lds(
        (const __attribute__((address_space(1))) unsigned int*)g,
        (__attribute__((address_space(3))) unsigned int*)l, 16, 0, 0);
}

// ---------------------------------------------------------------------------
// Kernel 1: prep — w2 pack + scaled biases only (zeroing via memset).
// ---------------------------------------------------------------------------
__global__ __launch_bounds__(256) void prep(
    const float* __restrict__ Wk, const float* __restrict__ bk,
    const float* __restrict__ Wq, const float* __restrict__ bq,
    const float* __restrict__ Wv, const float* __restrict__ bv,
    f16_t* __restrict__ w2, float* __restrict__ biasc) {
    int n = blockIdx.x;
    int t = threadIdx.x;
    const float scale = 0.08838834764831845f;  // HEAD^-0.5
    const float* W; const float* bias; float sc; int col;
    if (n < 128)      { W = Wq; bias = bq; sc = scale; col = n; }
    else if (n < 256) { W = Wk; bias = bk; sc = 1.0f;  col = n - 128; }
    else              { W = Wv; bias = bv; sc = 1.0f;  col = n - 256; }
    if (t < 128) {
        int k0 = t * 8;
        f16x8 v;
        #pragma unroll
        for (int i = 0; i < 8; ++i) v[i] = (f16_t)(W[(size_t)(k0 + i) * HD + col] * sc);
        *(f16x8*)&w2[(size_t)(n >> 4) * 16384 + (size_t)(k0 >> 3) * 128 + (n & 15) * 8] = v;
    }
    if (t == 0) biasc[n] = bias[col] * sc;
}

// ---------------------------------------------------------------------------
// Kernel 2: QKV GEMM — EXACT R3 v3 (43.0us verified best).
// ---------------------------------------------------------------------------
__global__ __launch_bounds__(256) void qkv_gemm(
    const float* __restrict__ X, const f16_t* __restrict__ w2,
    const float* __restrict__ biasc,
    f16_t* __restrict__ q2, f16_t* __restrict__ k2, f16_t* __restrict__ v2) {
    __shared__ f16_t Xs[2][64 * 72];
    __shared__ __align__(16) f16_t Bl[2][8 * 1024];

    int bid = blockIdx.x;
    int r8 = bid & 7, g = bid >> 3;
    int band = (g / 3) * 8 + r8;             // 64-row band, XCD-affine
    int i = g % 3;
    int m0 = band * 64, n0 = i * 128;
    int tid = threadIdx.x;
    int lane = tid & 63, w = tid >> 6;
    int quad = lane >> 4, l15 = lane & 15;
    int msub = (w & 1) * 32, nsub = (w >> 1) * 64;

    int srow = tid >> 2;           // 0..63
    int scg  = (tid & 3) * 16;     // 16-float group within BK=64

    const float* xrow = X + (size_t)(m0 + srow) * EMB + scg;
    const f16_t* bbase = w2 + (size_t)(n0 >> 4) * 16384;

    f32x4 acc[2][4] = {};
    float4 pf[4];

    auto loadA = [&](int kc) {
        #pragma unroll
        for (int u = 0; u < 4; ++u) pf[u] = *(const float4*)(xrow + kc * 64 + u * 4);
    };
    auto stageB = [&](int kc, int buf) {
        const f16_t* bsrc = bbase + (size_t)kc * 1024;
        #pragma unroll
        for (int ii = 0; ii < 4; ++ii) {
            int D = tid * 16 + ii * 4096;                 // byte offset in 16KB
            g2l(bsrc + (size_t)(D >> 11) * 16384 + ((D & 2047) >> 1),
                &Bl[buf][D >> 1]);
        }
    };
    auto stageA = [&](int buf) {
        union { f16_t h[8]; uint4 u4; } p0, p1;
        p0.h[0] = (f16_t)pf[0].x; p0.h[1] = (f16_t)pf[0].y;
        p0.h[2] = (f16_t)pf[0].z; p0.h[3] = (f16_t)pf[0].w;
        p0.h[4] = (f16_t)pf[1].x; p0.h[5] = (f16_t)pf[1].y;
        p0.h[6] = (f16_t)pf[1].z; p0.h[7] = (f16_t)pf[1].w;
        p1.h[0] = (f16_t)pf[2].x; p1.h[1] = (f16_t)pf[2].y;
        p1.h[2] = (f16_t)pf[2].z; p1.h[3] = (f16_t)pf[2].w;
        p1.h[4] = (f16_t)pf[3].x; p1.h[5] = (f16_t)pf[3].y;
        p1.h[6] = (f16_t)pf[3].z; p1.h[7] = (f16_t)pf[3].w;
        *(uint4*)&Xs[buf][srow * 72 + scg] = p0.u4;
        *(uint4*)&Xs[buf][srow * 72 + scg + 8] = p1.u4;
    };
    auto compute = [&](int buf) {
        #pragma unroll
        for (int ks = 0; ks < 2; ++ks) {
            f16x8 afr0 = *(const f16x8*)&Xs[buf][(msub + l15) * 72 + ks * 32 + quad * 8];
            f16x8 afr1 = *(const f16x8*)&Xs[buf][(msub + 16 + l15) * 72 + ks * 32 + quad * 8];
            #pragma unroll
            for (int nf = 0; nf < 4; ++nf) {
                int ntl = (nsub >> 4) + nf;
                f16x8 bfr = *(const f16x8*)&Bl[buf][ntl * 1024 + (ks * 4 + quad) * 128 + l15 * 8];
                acc[0][nf] = __builtin_amdgcn_mfma_f32_16x16x32_f16(afr0, bfr, acc[0][nf], 0, 0, 0);
                acc[1][nf] = __builtin_amdgcn_mfma_f32_16x16x32_f16(afr1, bfr, acc[1][nf], 0, 0, 0);
            }
        }
    };

    // prologue: fill buffer 0
    loadA(0);
    stageB(0, 0);
    stageA(0);
    __syncthreads();

    for (int kc = 0; kc < 16; ++kc) {
        int cur = kc & 1, nxt = cur ^ 1;
        if (kc + 1 < 16) {
            loadA(kc + 1);
            stageB(kc + 1, nxt);
        }
        compute(cur);
        if (kc + 1 < 16) stageA(nxt);
        __syncthreads();
    }

    // epilogue -> tiled layouts
    #pragma unroll
    for (int nf = 0; nf < 4; ++nf) {
        int ng = n0 + nsub + nf * 16 + l15;
        float bval = biasc[ng];
        #pragma unroll
        for (int mf = 0; mf < 2; ++mf) {
            int rowg = m0 + msub + mf * 16 + quad * 4;
            f32x4 a = acc[mf][nf];
            if (ng < 256) {
                f16_t* dst = (ng < 128) ? q2 : k2;
                int c = ng & 127;
                #pragma unroll
                for (int r = 0; r < 4; ++r) {
                    int row = rowg + r;
                    dst[(size_t)(row >> 4) * 2048 + (c >> 3) * 128 + (row & 15) * 8 + (c & 7)]
                        = (f16_t)(a[r] + bval);
                }
            } else {
                int h = ng - 256;
                f16x4 hv;
                #pragma unroll
                for (int r = 0; r < 4; ++r) hv[r] = (f16_t)(a[r] + bval);
                *(f16x4*)&v2[(size_t)(rowg >> 3) * 1024 + h * 8 + (rowg & 7)] = hv;
            }
        }
    }
}

// ---------------------------------------------------------------------------
// Kernel 3: column sums — R4 v2 (barrier-free, direct L2 reads). Unchanged.
// ---------------------------------------------------------------------------
__global__ __launch_bounds__(256, 4) void col_stats(
    const f16_t* __restrict__ q2, const f16_t* __restrict__ k2,
    float* __restrict__ colsum) {
    int bid = blockIdx.x;
    int b = bid & 7;
    int item = 143 - (bid >> 3);
    int cg = 0, slab = 0, cum = 0;
    for (int c = 0; c < 32; ++c) {
        int n = (32 - c + 3) >> 2;
        if (item < cum + n) { cg = c; slab = item - cum; break; }
        cum += n;
    }
    int tc0 = cg + slab * 4, tc1 = min(tc0 + 4, 32);

    int tid = threadIdx.x, lane = tid & 63, w = tid >> 6;
    int quad = lane >> 4, l15 = lane & 15;
    int brow = b * 128;
    size_t base = (size_t)b * T_SEQ;

    f16x8 bfrs[4][4];
    #pragma unroll
    for (int st = 0; st < 4; ++st) {
        const f16_t* kt = k2 + (size_t)(brow + cg * 4 + st) * 2048 + l15 * 8;
        #pragma unroll
        for (int kf = 0; kf < 4; ++kf)
            bfrs[st][kf] = *(const f16x8*)(kt + (kf * 4 + quad) * 128);
    }

    float lacc[4] = {0.f, 0.f, 0.f, 0.f};

    for (int tc = tc0; tc < tc1; ++tc) {
        int tb = tc * 64;
        f16x8 afr[4];
        const f16_t* qt = q2 + (size_t)(brow + tc * 4 + w) * 2048 + l15 * 8;
        #pragma unroll
        for (int kf = 0; kf < 4; ++kf)
            afr[kf] = *(const f16x8*)(qt + (kf * 4 + quad) * 128);
        #pragma unroll
        for (int st = 0; st < 4; ++st) {
            f32x4 s = {};
            #pragma unroll
            for (int kf = 0; kf < 4; ++kf)
                s = __builtin_amdgcn_mfma_f32_16x16x32_f16(afr[kf], bfrs[st][kf], s, 0, 0, 0);
            int scol = cg * 64 + st * 16 + l15;
            #pragma unroll
            for (int r = 0; r < 4; ++r) {
                int t = tb + w * 16 + quad * 4 + r;
                if (t >= scol) lacc[st] += __expf(s[r]);
            }
        }
    }

    #pragma unroll
    for (int st = 0; st < 4; ++st) {
        float v = lacc[st];
        v += __shfl_xor(v, 16, 64);
        v += __shfl_xor(v, 32, 64);
        if (quad == 0) atomicAdd(&colsum[base + cg * 64 + st * 16 + l15], v);
    }
}

// ---------------------------------------------------------------------------
// Kernel 4 (v4): single-barrier pipelined. K direct->regs (wave-private
// tile), V direct->regs (L2), Pl double-buffered. One __syncthreads per
// chunk; prefetch of chunk c+1 issued AFTER the barrier so PV(c) covers it.
// Manual 2x ping-pong with named register sets (no runtime frag indexing).
// ---------------------------------------------------------------------------
__global__ __launch_bounds__(256, 3) void attn_out(
    const f16_t* __restrict__ q2, const f16_t* __restrict__ k2,
    const f16_t* __restrict__ v2, const float* __restrict__ colsum,
    float* __restrict__ out) {
    __shared__ __align__(16) f16_t Pl[2][32 * 72];

    int bid = blockIdx.x;
    int b = bid & 7;
    int item = 159 - (bid >> 3);
    int g = 0, slab = 0, cum = 0;
    for (int gg = 0; gg < 64; ++gg) {
        int n = (((gg >> 1) + 1) + 7) >> 3;
        if (item < cum + n) { g = gg; slab = item - cum; break; }
        cum += n;
    }
    int nch = (g >> 1) + 1;
    int c0 = slab * 8, c1 = min(c0 + 8, nch);
    int trow = g * 32;

    int tid = threadIdx.x, lane = tid & 63, w = tid >> 6;
    int quad = lane >> 4, l15 = lane & 15;
    int brow = b * 128;
    size_t base = (size_t)b * T_SEQ;

    f16x8 qfr[2][4];
    #pragma unroll
    for (int tt = 0; tt < 2; ++tt) {
        const f16_t* qt = q2 + (size_t)(brow + 2 * g + tt) * 2048 + l15 * 8;
        #pragma unroll
        for (int kf = 0; kf < 4; ++kf)
            qfr[tt][kf] = *(const f16x8*)(qt + (kf * 4 + quad) * 128);
    }

    f32x4 o[2][2] = {};

    f16x8 kA[4], kB[4];
    f16x8 vA[2][2], vB[2][2];
    float csA, csB;

    auto loadKVc = [&](int c, f16x8 (&k)[4], f16x8 (&v)[2][2], float& cs) {
        const f16_t* kt = k2 + (size_t)(brow + c * 4 + w) * 2048 + l15 * 8;
        #pragma unroll
        for (int kf = 0; kf < 4; ++kf)
            k[kf] = *(const f16x8*)(kt + (kf * 4 + quad) * 128);
        const f16_t* vt = v2 + ((size_t)(base + c * 64) >> 3) * 1024;
        #pragma unroll
        for (int kf2 = 0; kf2 < 2; ++kf2)
            #pragma unroll
            for (int hh = 0; hh < 2; ++hh)
                v[kf2][hh] = *(const f16x8*)&vt[(kf2 * 4 + quad) * 1024 +
                                                (w * 32 + hh * 16 + l15) * 8];
        cs = colsum[base + c * 64 + w * 16 + l15];
    };
    auto qkt = [&](int c, f16x8 (&k)[4], float cs, int pb) {
        float iv = 1.0f / cs;
        int scol = c * 64 + w * 16 + l15;
        #pragma unroll
        for (int tt = 0; tt < 2; ++tt) {
            f32x4 s = {};
            #pragma unroll
            for (int kf = 0; kf < 4; ++kf)
                s = __builtin_amdgcn_mfma_f32_16x16x32_f16(qfr[tt][kf], k[kf], s, 0, 0, 0);
            #pragma unroll
            for (int r = 0; r < 4; ++r) {
                int t = trow + tt * 16 + quad * 4 + r;
                float pv = (t >= scol) ? __expf(s[r]) * iv : 0.f;
                Pl[pb][(tt * 16 + quad * 4 + r) * 72 + w * 16 + l15] = (f16_t)pv;
            }
        }
    };
    auto pvstep = [&](f16x8 (&v)[2][2], int pb) {
        #pragma unroll
        for (int kf2 = 0; kf2 < 2; ++kf2) {
            f16x8 pa0 = *(const f16x8*)&Pl[pb][(l15) * 72 + kf2 * 32 + quad * 8];
            f16x8 pa1 = *(const f16x8*)&Pl[pb][(16 + l15) * 72 + kf2 * 32 + quad * 8];
            #pragma unroll
            for (int hh = 0; hh < 2; ++hh) {
                o[0][hh] = __builtin_amdgcn_mfma_f32_16x16x32_f16(pa0, v[kf2][hh], o[0][hh], 0, 0, 0);
                o[1][hh] = __builtin_amdgcn_mfma_f32_16x16x32_f16(pa1, v[kf2][hh], o[1][hh], 0, 0, 0);
            }
        }
    };

    int c = c0;
    loadKVc(c, kA, vA, csA);                 // prologue prefetch
    for (; c + 1 < c1; c += 2) {
        qkt(c, kA, csA, 0);
        __syncthreads();                     // Pl[0] visible; kA/vA consumed
        loadKVc(c + 1, kB, vB, csB);         // covered by pvstep below
        pvstep(vA, 0);
        qkt(c + 1, kB, csB, 1);
        __syncthreads();                     // Pl[1] visible
        if (c + 2 < c1) loadKVc(c + 2, kA, vA, csA);
        pvstep(vB, 1);
    }
    if (c < c1) {
        qkt(c, kA, csA, 0);
        __syncthreads();
        pvstep(vA, 0);
    }

    #pragma unroll
    for (int tt = 0; tt < 2; ++tt)
        #pragma unroll
        for (int hh = 0; hh < 2; ++hh)
            #pragma unroll
            for (int r = 0; r < 4; ++r)
                atomicAdd(&out[(base + trow + tt * 16 + quad * 4 + r) * HD + w * 32 + hh * 16 + l15],
                          o[tt][hh][r]);
}

// ---------------------------------------------------------------------------
extern "C" void kernel_launch(void* const* d_in, const int* in_sizes, int n_in,
                              void* d_out, int out_size, void* d_ws, size_t ws_size,
                              hipStream_t stream) {
    const float* X  = (const float*)d_in[0];
    const float* Wk = (const float*)d_in[1];
    const float* bk = (const float*)d_in[2];
    const float* Wq = (const float*)d_in[3];
    const float* bq = (const float*)d_in[4];
    const float* Wv = (const float*)d_in[5];
    const float* bv = (const float*)d_in[6];
    float* out = (float*)d_out;

    char* ws = (char*)d_ws;
    const size_t W2_B    = 24 * 16384 * 2;                   // 768 KiB
    const size_t BIAS_B  = 2048;
    const size_t QKV_B   = (size_t)NBATCH * T_SEQ * HD * 2;  // 4 MiB each
    f16_t* w2     = (f16_t*)ws;
    float* biasc  = (float*)(ws + W2_B);
    f16_t* q2     = (f16_t*)(ws + W2_B + BIAS_B);
    f16_t* k2     = (f16_t*)(ws + W2_B + BIAS_B + QKV_B);
    f16_t* v2     = (f16_t*)(ws + W2_B + BIAS_B + 2 * QKV_B);
    float* colsum = (float*)(ws + W2_B + BIAS_B + 3 * QKV_B);

    // zero out (8MB) + colsum (64KB) via stream-ordered memsets (capture-safe)
    hipMemsetAsync(out, 0, (size_t)NBATCH * T_SEQ * HD * sizeof(float), stream);
    hipMemsetAsync(colsum, 0, (size_t)NBATCH * T_SEQ * sizeof(float), stream);

    prep<<<dim3(384), dim3(256), 0, stream>>>(Wk, bk, Wq, bq, Wv, bv, w2, biasc);
    qkv_gemm<<<dim3(768), dim3(256), 0, stream>>>(X, w2, biasc, q2, k2, v2);
    col_stats<<<dim3(1152), dim3(256), 0, stream>>>(q2, k2, colsum);
    attn_out<<<dim3(1280), dim3(256), 0, stream>>>(q2, k2, v2, colsum, out);
}